// Round 5
// baseline (330.826 us; speedup 1.0000x reference)
//
#include <hip/hip_runtime.h>

#define B_ 4
#define T_ 2048
#define H_ 8
#define E_ 64
#define KDIM 512

typedef unsigned short ushort_t;
typedef __attribute__((ext_vector_type(4))) float f32x4;
typedef __attribute__((ext_vector_type(4))) int i32x4;
typedef __attribute__((ext_vector_type(8))) short s16x8;

// fold (1/64^0.25) * sqrt(log2(e)) into both Wq and Wk -> logits arrive pre-multiplied by log2(e)
#define QK_SCALE 0.42466043f

__device__ __forceinline__ ushort_t f2bf(float f) {   // RNE
  unsigned u = __builtin_bit_cast(unsigned, f);
  u += 0x7fffu + ((u >> 16) & 1u);
  return (ushort_t)(u >> 16);
}
__device__ __forceinline__ unsigned pk2(float a, float b) {  // RNE pack
  return (unsigned)f2bf(a) | ((unsigned)f2bf(b) << 16);
}
// truncating pack, single v_perm_b32: dst = {hi16(b), hi16(a)}
__device__ __forceinline__ unsigned pk2t(float a, float b) {
  return __builtin_amdgcn_perm(__builtin_bit_cast(unsigned, b),
                               __builtin_bit_cast(unsigned, a), 0x07060302u);
}
// async global->LDS, 16B per lane, LDS dest = wave-uniform base + lane*16
__device__ __forceinline__ void gl2lds16(const void* g, void* l) {
  __builtin_amdgcn_global_load_lds((const __attribute__((address_space(1))) unsigned*)g,
                                   (__attribute__((address_space(3))) unsigned*)l, 16, 0, 0);
}

// ---------------- weight prep: LDS-tiled transpose to [N][K] bf16, fold scales ------
__global__ void k_prep(const float* __restrict__ Wq, const float* __restrict__ Wk,
                       const float* __restrict__ Wv, ushort_t* __restrict__ wt) {
  __shared__ ushort_t tile[64][66];
  int z = blockIdx.z;
  const float* W = (z == 0) ? Wq : (z == 1 ? Wk : Wv);
  float scale = (z < 2) ? QK_SCALE : 1.0f;
  int k0 = blockIdx.y << 6, n0 = blockIdx.x << 6;
  int rr = threadIdx.x >> 6, cc = threadIdx.x & 63;
  for (int p = 0; p < 16; p++) {
    int kl = p * 4 + rr;
    tile[cc][kl] = f2bf(W[(size_t)(k0 + kl) * 512 + n0 + cc] * scale);
  }
  __syncthreads();
  int kp2 = threadIdx.x & 31, nr = threadIdx.x >> 5;
  unsigned* wt32 = (unsigned*)(wt + (size_t)z * 262144);
  for (int p = 0; p < 8; p++) {
    int nl = p * 8 + nr;
    unsigned val = (unsigned)tile[nl][kp2 * 2] | ((unsigned)tile[nl][kp2 * 2 + 1] << 16);
    wt32[(size_t)(n0 + nl) * 256 + (k0 >> 1) + kp2] = val;
  }
}

// ---------------- merge-weight softmax over heads: wgt[h][e] ------------------------
__global__ void k_wgt(const float* __restrict__ mw, float* __restrict__ wgt) {
  int e = threadIdx.x;  // 64 threads
  float w[8], wmax = -1e30f;
  for (int h = 0; h < 8; h++) { w[h] = mw[h * 64 + e]; wmax = fmaxf(wmax, w[h]); }
  float wsum = 0.f;
  for (int h = 0; h < 8; h++) { w[h] = __expf(w[h] - wmax); wsum += w[h]; }
  float inv = 1.f / wsum;
  for (int h = 0; h < 8; h++) wgt[h * 64 + e] = w[h] * inv;
}

// ---------------- QKV projection: m97 GEMM, 128m x 256n tile, BK=64 -----------------
// A staged fp32 via gl_lds (swizzled), converted RNE at frag read; B staged bf16.
// For V (which==2) the MFMA operands are SWAPPED: C = W·X^T gives V^T directly in
// C-layout -> V stores become 32B-contiguous without any extra LDS pass.
__global__ __launch_bounds__(256, 2) void k_proj(
    const float* __restrict__ obs, const float* __restrict__ st,
    const ushort_t* __restrict__ wt,
    ushort_t* __restrict__ qo, ushort_t* __restrict__ ko, ushort_t* __restrict__ vto) {
  __shared__ __align__(16) float    As[128 * 64];   // 32 KB
  __shared__ __align__(16) ushort_t Bs[256 * 64];   // 32 KB

  int id = blockIdx.x;          // 384 = 3 which x 2 nt x 64 m
  int which = id >> 7;
  int nt = (id >> 6) & 1;
  int m0 = (id & 63) << 7, n0 = nt << 8;
  const float* X = (which == 0) ? obs : st;
  const ushort_t* W = wt + which * 262144;

  int tid = threadIdx.x, wave = tid >> 6, lane = tid & 63;
  int l15 = lane & 15, quad = lane >> 4;
  int wm = wave & 1, wn = wave >> 1;

  f32x4 acc[4][8];
  for (int i = 0; i < 4; i++)
    for (int j = 0; j < 8; j++) acc[i][j] = (f32x4){0.f, 0.f, 0.f, 0.f};

  int arl = lane >> 4, ap = lane & 15;  // A: 4 rows/instr, 16 chunks/row
  int brl = lane >> 3, bp = lane & 7;   // B: 8 rows/instr, 8 chunks/row

  for (int k0 = 0; k0 < KDIM; k0 += 64) {
    for (int ii = 0; ii < 8; ii++) {
      int r = wave * 32 + ii * 4 + arl;
      int lc = ap ^ ((r & 7) << 1);
      gl2lds16(X + (size_t)(m0 + r) * KDIM + k0 + lc * 4, &As[(wave * 32 + ii * 4) * 64]);
    }
    for (int ii = 0; ii < 8; ii++) {
      int r = wave * 64 + ii * 8 + brl;
      int lc = bp ^ (r & 7);
      gl2lds16(W + (size_t)(n0 + r) * KDIM + k0 + lc * 8, &Bs[(wave * 64 + ii * 8) * 64]);
    }
    __syncthreads();

    for (int kc = 0; kc < 2; kc++) {
      s16x8 a[4], b[8];
      for (int i = 0; i < 4; i++) {
        int mr = wm * 64 + i * 16 + l15;
        int pc = (kc * 8 + quad * 2) ^ ((l15 & 7) << 1);
        const float* ap2 = &As[mr * 64 + pc * 4];
        float4 x0 = *(const float4*)ap2;
        float4 x1 = *(const float4*)(ap2 + 4);
        i32x4 d;
        d[0] = (int)pk2(x0.x, x0.y);
        d[1] = (int)pk2(x0.z, x0.w);
        d[2] = (int)pk2(x1.x, x1.y);
        d[3] = (int)pk2(x1.z, x1.w);
        a[i] = __builtin_bit_cast(s16x8, d);
      }
      for (int j = 0; j < 8; j++) {
        int nr = wn * 128 + j * 16 + l15;
        int pc = (kc * 4 + quad) ^ (l15 & 7);
        b[j] = *(const s16x8*)&Bs[nr * 64 + pc * 8];
      }
      if (which == 2) {
        for (int i = 0; i < 4; i++)
          for (int j = 0; j < 8; j++)
            acc[i][j] = __builtin_amdgcn_mfma_f32_16x16x32_bf16(b[j], a[i], acc[i][j], 0, 0, 0);
      } else {
        for (int i = 0; i < 4; i++)
          for (int j = 0; j < 8; j++)
            acc[i][j] = __builtin_amdgcn_mfma_f32_16x16x32_bf16(a[i], b[j], acc[i][j], 0, 0, 0);
      }
    }
    __syncthreads();
  }

  if (which != 2) {
    ushort_t* dst = (which == 0) ? qo : ko;
    for (int i = 0; i < 4; i++) {
      int grow = m0 + wm * 64 + i * 16 + quad * 4;
      for (int j = 0; j < 8; j++) {
        int gcol = n0 + wn * 128 + j * 16 + l15;
        int h = gcol >> 6, e = gcol & 63;
        for (int r = 0; r < 4; r++) {
          int row = grow + r;
          int bb = row >> 11, t = row & 2047;
          int bh = bb * H_ + h;
          dst[(((size_t)bh * T_ + t) << 6) + e] = f2bf(acc[i][j][r]);
        }
      }
    }
  } else {
    // swapped: C row = W-col (h,e), C col = X-row (t); lanes give 16 consecutive t
    for (int i = 0; i < 4; i++) {
      int row = m0 + wm * 64 + i * 16 + l15;
      int bb = row >> 11, t = row & 2047;
      for (int j = 0; j < 8; j++) {
        for (int r = 0; r < 4; r++) {
          int gcol = n0 + wn * 128 + j * 16 + quad * 4 + r;
          int h = gcol >> 6, e = gcol & 63;
          int bh = bb * H_ + h;
          vto[((size_t)(bh << 6) + e) * T_ + t] = f2bf(acc[i][j][r]);
        }
      }
    }
  }
}

// ---------------- flash attention v4: S^T trick + double-buffered staging -----------
// 1 barrier/iter: prefetch tile kt+1 right after the barrier, compute kt; the vmcnt
// drain at the NEXT barrier lands after a full compute phase (staging hidden).
// P packed with v_perm (trunc; bias cancels in l-normalization). l via ones-MFMA.
__global__ __launch_bounds__(256, 2) void k_attn(
    const ushort_t* __restrict__ q, const ushort_t* __restrict__ k,
    const ushort_t* __restrict__ vt, const float* __restrict__ wgt,
    float* __restrict__ out) {
  __shared__ __align__(16) ushort_t ks[2][128 * 64];  // 2 x 16 KB
  __shared__ __align__(16) ushort_t vs[2][64 * 128];  // 2 x 16 KB

  int id = blockIdx.x;      // 512; bh fastest -> 4 heads/XCD (K+V L2-resident)
  int bh = id & 31, qt = id >> 5;
  int tid = threadIdx.x, wave = tid >> 6, lane = tid & 63;
  int l15 = lane & 15, quad = lane >> 4;

  // Q B-frags for 2 query sub-tiles: B[k=e=quad*8+j][n=q=l15]
  s16x8 qf[2][2];
  for (int qs = 0; qs < 2; qs++) {
    const ushort_t* qp =
        q + (((size_t)bh * T_ + qt * 128 + wave * 32 + qs * 16 + l15) << 6) + quad * 8;
    qf[qs][0] = *(const s16x8*)qp;
    qf[qs][1] = *(const s16x8*)(qp + 32);
  }

  f32x4 o[2][4];
  for (int qs = 0; qs < 2; qs++)
    for (int j = 0; j < 4; j++) o[qs][j] = (f32x4){0.f, 0.f, 0.f, 0.f};
  f32x4 lacc[2] = {(f32x4){0.f, 0.f, 0.f, 0.f}, (f32x4){0.f, 0.f, 0.f, 0.f}};
  const s16x8 ones = {16256, 16256, 16256, 16256, 16256, 16256, 16256, 16256};  // bf16 1.0

  // staging pointers (permutation + swizzle folded in), advanced per kt
  int krl = lane >> 3, kp = lane & 7;
  int vrl = lane >> 4, vp = lane & 15;
  const ushort_t* kbase = k + ((size_t)bh * T_ << 6);
  const ushort_t* vbase = vt + ((size_t)bh << 6) * T_;
  const ushort_t* kptr[4];
  const ushort_t* vptr[4];
  for (int ii = 0; ii < 4; ii++) {
    int r = wave * 32 + ii * 8 + krl;
    int gkey = (r & 96) + (((r >> 2) & 3) << 3) + (((r >> 4) & 1) << 2) + (r & 3);
    int lc = kp ^ (r & 7);
    kptr[ii] = kbase + ((size_t)gkey << 6) + lc * 8;
    int e = wave * 16 + ii * 4 + vrl;
    int lcv = vp ^ (e & 15);
    vptr[ii] = vbase + (size_t)e * T_ + lcv * 8;
  }

#define STAGE(buf)                                                        \
  do {                                                                    \
    for (int ii = 0; ii < 4; ii++) {                                      \
      gl2lds16(kptr[ii], &ks[buf][(wave * 32 + ii * 8) * 64]);            \
      gl2lds16(vptr[ii], &vs[buf][(wave * 16 + ii * 4) * 128]);           \
      kptr[ii] += 128 * 64;                                               \
      vptr[ii] += 128;                                                    \
    }                                                                     \
  } while (0)

  STAGE(0);
  for (int kt = 0; kt < 16; kt++) {
    __builtin_amdgcn_s_waitcnt(0x0F70);  // vmcnt(0): prev staging landed
    __syncthreads();
    if (kt < 15) STAGE((kt + 1) & 1);
    const ushort_t* ksb = ks[kt & 1];
    const ushort_t* vsb = vs[kt & 1];

    // S^T chunks -> exp2 -> perm-pack P^T B-frags, entirely in-lane
    s16x8 bfr[2][4];
    for (int c = 0; c < 4; c++) {
      f32x4 s0[2], s1[2];
      for (int qs = 0; qs < 2; qs++) {
        s0[qs] = (f32x4){0.f, 0.f, 0.f, 0.f};
        s1[qs] = (f32x4){0.f, 0.f, 0.f, 0.f};
      }
      for (int kc = 0; kc < 2; kc++) {
        int pc = (kc * 4 + quad) ^ (l15 & 7);
        s16x8 k0f = *(const s16x8*)&ksb[(c * 32 + l15) * 64 + pc * 8];
        s16x8 k1f = *(const s16x8*)&ksb[(c * 32 + 16 + l15) * 64 + pc * 8];
        for (int qs = 0; qs < 2; qs++) {
          s0[qs] = __builtin_amdgcn_mfma_f32_16x16x32_bf16(k0f, qf[qs][kc], s0[qs], 0, 0, 0);
          s1[qs] = __builtin_amdgcn_mfma_f32_16x16x32_bf16(k1f, qf[qs][kc], s1[qs], 0, 0, 0);
        }
      }
      for (int qs = 0; qs < 2; qs++) {
        i32x4 d;
        d[0] = (int)pk2t(exp2f(s0[qs][0]), exp2f(s0[qs][1]));
        d[1] = (int)pk2t(exp2f(s0[qs][2]), exp2f(s0[qs][3]));
        d[2] = (int)pk2t(exp2f(s1[qs][0]), exp2f(s1[qs][1]));
        d[3] = (int)pk2t(exp2f(s1[qs][2]), exp2f(s1[qs][3]));
        bfr[qs][c] = __builtin_bit_cast(s16x8, d);
      }
    }

    // O^T += V^T · P ; l += 1 · P  (V frags shared across both query sub-tiles)
    for (int c = 0; c < 4; c++) {
      lacc[0] = __builtin_amdgcn_mfma_f32_16x16x32_bf16(ones, bfr[0][c], lacc[0], 0, 0, 0);
      lacc[1] = __builtin_amdgcn_mfma_f32_16x16x32_bf16(ones, bfr[1][c], lacc[1], 0, 0, 0);
      for (int et = 0; et < 4; et++) {
        int pc = (c * 4 + quad) ^ l15;
        s16x8 vf = *(const s16x8*)&vsb[(et * 16 + l15) * 128 + pc * 8];
        o[0][et] = __builtin_amdgcn_mfma_f32_16x16x32_bf16(vf, bfr[0][c], o[0][et], 0, 0, 0);
        o[1][et] = __builtin_amdgcn_mfma_f32_16x16x32_bf16(vf, bfr[1][c], o[1][et], 0, 0, 0);
      }
    }
  }
#undef STAGE

  // epilogue: every lane has its own query's l in lacc[qs][0]; weighted atomics
  int bb = bh >> 3, hh = bh & 7;
  for (int qs = 0; qs < 2; qs++) {
    float inv = 1.f / lacc[qs][0];
    int t = qt * 128 + wave * 32 + qs * 16 + l15;
    for (int et = 0; et < 4; et++)
      for (int r = 0; r < 4; r++) {
        int e = et * 16 + quad * 4 + r;
        float val = o[qs][et][r] * inv * wgt[hh * 64 + e];
        atomicAdd(&out[(((size_t)bb * T_ + t) << 6) + e], val);
      }
  }
}

extern "C" void kernel_launch(void* const* d_in, const int* in_sizes, int n_in,
                              void* d_out, int out_size, void* d_ws, size_t ws_size,
                              hipStream_t stream) {
  const float* obs = (const float*)d_in[0];
  const float* st  = (const float*)d_in[1];
  const float* Wq  = (const float*)d_in[2];
  const float* Wk  = (const float*)d_in[3];
  const float* Wv  = (const float*)d_in[4];
  const float* mw  = (const float*)d_in[5];

  // ws layout (26 MB, identical to rounds 2-4 proven layout)
  const size_t WS_NEEDED = 27262976;
  char* ws = (char*)d_ws;
  ushort_t* wt  = (ushort_t*)ws;                     // 1.5 MB
  float*    wgt = (float*)(ws + 1572864u);           // 2 KB
  ushort_t* qo  = (ushort_t*)(ws + 2097152u);        // [B,H,T,E] bf16, 8 MB
  ushort_t* ko  = (ushort_t*)(ws + 10485760u);       // [B,H,T,E] bf16, 8 MB
  ushort_t* vto = (ushort_t*)(ws + 18874368u);       // [B,H,E,T] bf16, 8 MB
  float*    out = (float*)d_out;

  hipMemsetAsync(d_out, 0, (size_t)out_size * sizeof(float), stream);
  if (ws_size < WS_NEEDED) return;

  hipLaunchKernelGGL(k_prep, dim3(8, 8, 3), dim3(256), 0, stream, Wq, Wk, Wv, wt);
  hipLaunchKernelGGL(k_wgt,  dim3(1),       dim3(64),  0, stream, mw, wgt);
  hipLaunchKernelGGL(k_proj, dim3(384),     dim3(256), 0, stream, obs, st, wt, qo, ko, vto);
  hipLaunchKernelGGL(k_attn, dim3(512),     dim3(256), 0, stream, qo, ko, vto, wgt, out);
}

// Round 6
// 207.760 us; speedup vs baseline: 1.5923x; 1.5923x over previous
//
#include <hip/hip_runtime.h>

#define B_ 4
#define T_ 2048
#define H_ 8
#define E_ 64
#define KDIM 512

typedef unsigned short ushort_t;
typedef __attribute__((ext_vector_type(4))) float f32x4;
typedef __attribute__((ext_vector_type(4))) int i32x4;
typedef __attribute__((ext_vector_type(8))) short s16x8;

// fold (1/64^0.25) * sqrt(log2(e)) into both Wq and Wk -> logits arrive pre-multiplied by log2(e)
#define QK_SCALE 0.42466043f

__device__ __forceinline__ ushort_t f2bf(float f) {   // RNE
  unsigned u = __builtin_bit_cast(unsigned, f);
  u += 0x7fffu + ((u >> 16) & 1u);
  return (ushort_t)(u >> 16);
}
__device__ __forceinline__ unsigned pk2(float a, float b) {  // RNE pack
  return (unsigned)f2bf(a) | ((unsigned)f2bf(b) << 16);
}
// truncating pack, single v_perm_b32: dst = {hi16(b), hi16(a)}
__device__ __forceinline__ unsigned pk2t(float a, float b) {
  return __builtin_amdgcn_perm(__builtin_bit_cast(unsigned, b),
                               __builtin_bit_cast(unsigned, a), 0x07060302u);
}
__device__ __forceinline__ float e2(float x) { return __builtin_amdgcn_exp2f(x); }
// async global->LDS, 16B per lane, LDS dest = wave-uniform base + lane*16
__device__ __forceinline__ void gl2lds16(const void* g, void* l) {
  __builtin_amdgcn_global_load_lds((const __attribute__((address_space(1))) unsigned*)g,
                                   (__attribute__((address_space(3))) unsigned*)l, 16, 0, 0);
}

// ---------------- weight prep: LDS-tiled transpose to [N][K] bf16, fold scales ------
__global__ void k_prep(const float* __restrict__ Wq, const float* __restrict__ Wk,
                       const float* __restrict__ Wv, ushort_t* __restrict__ wt) {
  __shared__ ushort_t tile[64][66];
  int z = blockIdx.z;
  const float* W = (z == 0) ? Wq : (z == 1 ? Wk : Wv);
  float scale = (z < 2) ? QK_SCALE : 1.0f;
  int k0 = blockIdx.y << 6, n0 = blockIdx.x << 6;
  int rr = threadIdx.x >> 6, cc = threadIdx.x & 63;
  for (int p = 0; p < 16; p++) {
    int kl = p * 4 + rr;
    tile[cc][kl] = f2bf(W[(size_t)(k0 + kl) * 512 + n0 + cc] * scale);
  }
  __syncthreads();
  int kp2 = threadIdx.x & 31, nr = threadIdx.x >> 5;
  unsigned* wt32 = (unsigned*)(wt + (size_t)z * 262144);
  for (int p = 0; p < 8; p++) {
    int nl = p * 8 + nr;
    unsigned val = (unsigned)tile[nl][kp2 * 2] | ((unsigned)tile[nl][kp2 * 2 + 1] << 16);
    wt32[(size_t)(n0 + nl) * 256 + (k0 >> 1) + kp2] = val;
  }
}

// ---------------- merge-weight softmax over heads: wgt[h][e] ------------------------
__global__ void k_wgt(const float* __restrict__ mw, float* __restrict__ wgt) {
  int e = threadIdx.x;  // 64 threads
  float w[8], wmax = -1e30f;
  for (int h = 0; h < 8; h++) { w[h] = mw[h * 64 + e]; wmax = fmaxf(wmax, w[h]); }
  float wsum = 0.f;
  for (int h = 0; h < 8; h++) { w[h] = __expf(w[h] - wmax); wsum += w[h]; }
  float inv = 1.f / wsum;
  for (int h = 0; h < 8; h++) wgt[h * 64 + e] = w[h] * inv;
}

// ---------------- QKV projection v6: A dbuf-LDS, B register-direct (L2-hot) ---------
// 128m x 128n tile, BK=64, acc[4][4]=64 AGPR per wave (NO spills). B-loads issued
// BEFORE the A-prefetch so their waitcnt is vmcnt(8), keeping the prefetch in flight.
// Grid swizzle: the 4 n-tile siblings of an m-block share an XCD -> A read once from
// HBM, siblings hit L2. For V the MFMA operands are swapped (C = W·X^T = V^T direct).
__global__ __launch_bounds__(256, 2) void k_proj(
    const float* __restrict__ obs, const float* __restrict__ st,
    const ushort_t* __restrict__ wt,
    ushort_t* __restrict__ qo, ushort_t* __restrict__ ko, ushort_t* __restrict__ vto) {
  __shared__ __align__(16) float As[2][128 * 64];   // 2 x 32 KB

  int id = blockIdx.x;              // 768
  int xcd = id & 7, nt = (id >> 3) & 3, ghi = id >> 5;
  int g = ghi * 8 + xcd;            // sibling group 0..191, all 4 nt share xcd
  int which = g >> 6, mb = g & 63;
  int m0 = mb << 7, n0 = nt << 7;
  const float* X = (which == 0) ? obs : st;
  const ushort_t* W = wt + which * 262144;

  int tid = threadIdx.x, wave = tid >> 6, lane = tid & 63;
  int l15 = lane & 15, quad = lane >> 4;
  int wm = wave & 1, wn = wave >> 1;

  f32x4 acc[4][4];
  for (int i = 0; i < 4; i++)
    for (int j = 0; j < 4; j++) acc[i][j] = (f32x4){0.f, 0.f, 0.f, 0.f};

  int arl = lane >> 4, ap = lane & 15;  // A stage: 4 rows/instr, 16 chunks/row

#define STAGEA(buf, k0)                                                          \
  do {                                                                           \
    for (int ii = 0; ii < 8; ii++) {                                             \
      int r = wave * 32 + ii * 4 + arl;                                          \
      int lc = ap ^ ((r & 7) << 1);                                              \
      gl2lds16(X + (size_t)(m0 + r) * KDIM + (k0) + lc * 4,                      \
               &As[buf][(wave * 32 + ii * 4) * 64]);                             \
    }                                                                            \
  } while (0)

  // B row pointers (advance by 64 per k-iter)
  const ushort_t* wb[4];
  for (int j = 0; j < 4; j++)
    wb[j] = W + (size_t)(n0 + wn * 64 + j * 16 + l15) * KDIM + quad * 8;

  STAGEA(0, 0);
  __builtin_amdgcn_s_waitcnt(0x0F70);  // vmcnt(0)
  __syncthreads();

  for (int kt = 0; kt < 8; kt++) {
    // 1) B register loads FIRST (their waitcnt leaves the A-prefetch outstanding)
    s16x8 b[2][4];
    for (int kc = 0; kc < 2; kc++)
      for (int j = 0; j < 4; j++) b[kc][j] = *(const s16x8*)(wb[j] + kc * 32);
    for (int j = 0; j < 4; j++) wb[j] += 64;
    // 2) prefetch next A tile
    if (kt < 7) STAGEA((kt + 1) & 1, kt * 64 + 64);
    // 3) compute on current A tile
    const float* asb = As[kt & 1];
    for (int kc = 0; kc < 2; kc++) {
      s16x8 a[4];
      for (int i = 0; i < 4; i++) {
        int mr = wm * 64 + i * 16 + l15;
        int pc = (kc * 8 + quad * 2) ^ ((l15 & 7) << 1);
        const float* ap2 = &asb[mr * 64 + pc * 4];
        float4 x0 = *(const float4*)ap2;
        float4 x1 = *(const float4*)(ap2 + 4);
        i32x4 d;
        d[0] = (int)pk2(x0.x, x0.y);
        d[1] = (int)pk2(x0.z, x0.w);
        d[2] = (int)pk2(x1.x, x1.y);
        d[3] = (int)pk2(x1.z, x1.w);
        a[i] = __builtin_bit_cast(s16x8, d);
      }
      if (which == 2) {
        for (int i = 0; i < 4; i++)
          for (int j = 0; j < 4; j++)
            acc[i][j] = __builtin_amdgcn_mfma_f32_16x16x32_bf16(b[kc][j], a[i], acc[i][j], 0, 0, 0);
      } else {
        for (int i = 0; i < 4; i++)
          for (int j = 0; j < 4; j++)
            acc[i][j] = __builtin_amdgcn_mfma_f32_16x16x32_bf16(a[i], b[kc][j], acc[i][j], 0, 0, 0);
      }
    }
    __builtin_amdgcn_s_waitcnt(0x0F70);  // vmcnt(0): next A landed
    __syncthreads();
  }
#undef STAGEA

  if (which != 2) {
    ushort_t* dst = (which == 0) ? qo : ko;
    for (int i = 0; i < 4; i++) {
      int grow = m0 + wm * 64 + i * 16 + quad * 4;
      for (int j = 0; j < 4; j++) {
        int gcol = n0 + wn * 64 + j * 16 + l15;
        int h = gcol >> 6, e = gcol & 63;
        for (int r = 0; r < 4; r++) {
          int row = grow + r;
          int bb = row >> 11, t = row & 2047;
          int bh = bb * H_ + h;
          dst[(((size_t)bh * T_ + t) << 6) + e] = f2bf(acc[i][j][r]);
        }
      }
    }
  } else {
    // swapped: C row = W-col (h,e), C col = X-row (t); 16 consecutive t per store
    for (int i = 0; i < 4; i++) {
      int row = m0 + wm * 64 + i * 16 + l15;
      int bb = row >> 11, t = row & 2047;
      for (int j = 0; j < 4; j++) {
        for (int r = 0; r < 4; r++) {
          int gcol = n0 + wn * 64 + j * 16 + quad * 4 + r;
          int h = gcol >> 6, e = gcol & 63;
          int bh = bb * H_ + h;
          vto[((size_t)(bh << 6) + e) * T_ + t] = f2bf(acc[i][j][r]);
        }
      }
    }
  }
}

// ---------------- flash attention v5: round-5 structure + raw v_exp_f32 -------------
__global__ __launch_bounds__(256, 2) void k_attn(
    const ushort_t* __restrict__ q, const ushort_t* __restrict__ k,
    const ushort_t* __restrict__ vt, const float* __restrict__ wgt,
    float* __restrict__ out) {
  __shared__ __align__(16) ushort_t ks[2][128 * 64];  // 2 x 16 KB
  __shared__ __align__(16) ushort_t vs[2][64 * 128];  // 2 x 16 KB

  int id = blockIdx.x;      // 512; bh fastest -> 4 heads/XCD (K+V L2-resident)
  int bh = id & 31, qt = id >> 5;
  int tid = threadIdx.x, wave = tid >> 6, lane = tid & 63;
  int l15 = lane & 15, quad = lane >> 4;

  // Q B-frags for 2 query sub-tiles: B[k=e=quad*8+j][n=q=l15]
  s16x8 qf[2][2];
  for (int qs = 0; qs < 2; qs++) {
    const ushort_t* qp =
        q + (((size_t)bh * T_ + qt * 128 + wave * 32 + qs * 16 + l15) << 6) + quad * 8;
    qf[qs][0] = *(const s16x8*)qp;
    qf[qs][1] = *(const s16x8*)(qp + 32);
  }

  f32x4 o[2][4];
  for (int qs = 0; qs < 2; qs++)
    for (int j = 0; j < 4; j++) o[qs][j] = (f32x4){0.f, 0.f, 0.f, 0.f};
  f32x4 lacc[2] = {(f32x4){0.f, 0.f, 0.f, 0.f}, (f32x4){0.f, 0.f, 0.f, 0.f}};
  const s16x8 ones = {16256, 16256, 16256, 16256, 16256, 16256, 16256, 16256};  // bf16 1.0

  int krl = lane >> 3, kp = lane & 7;
  int vrl = lane >> 4, vp = lane & 15;
  const ushort_t* kbase = k + ((size_t)bh * T_ << 6);
  const ushort_t* vbase = vt + ((size_t)bh << 6) * T_;
  const ushort_t* kptr[4];
  const ushort_t* vptr[4];
  for (int ii = 0; ii < 4; ii++) {
    int r = wave * 32 + ii * 8 + krl;
    int gkey = (r & 96) + (((r >> 2) & 3) << 3) + (((r >> 4) & 1) << 2) + (r & 3);
    int lc = kp ^ (r & 7);
    kptr[ii] = kbase + ((size_t)gkey << 6) + lc * 8;
    int e = wave * 16 + ii * 4 + vrl;
    int lcv = vp ^ (e & 15);
    vptr[ii] = vbase + (size_t)e * T_ + lcv * 8;
  }

#define STAGE(buf)                                                        \
  do {                                                                    \
    for (int ii = 0; ii < 4; ii++) {                                      \
      gl2lds16(kptr[ii], &ks[buf][(wave * 32 + ii * 8) * 64]);            \
      gl2lds16(vptr[ii], &vs[buf][(wave * 16 + ii * 4) * 128]);           \
      kptr[ii] += 128 * 64;                                               \
      vptr[ii] += 128;                                                    \
    }                                                                     \
  } while (0)

  STAGE(0);
  for (int kt = 0; kt < 16; kt++) {
    __builtin_amdgcn_s_waitcnt(0x0F70);  // vmcnt(0): prev staging landed
    __syncthreads();
    if (kt < 15) STAGE((kt + 1) & 1);
    const ushort_t* ksb = ks[kt & 1];
    const ushort_t* vsb = vs[kt & 1];

    // S^T chunks -> v_exp_f32 -> perm-pack P^T B-frags, entirely in-lane
    s16x8 bfr[2][4];
    for (int c = 0; c < 4; c++) {
      f32x4 s0[2], s1[2];
      for (int qs = 0; qs < 2; qs++) {
        s0[qs] = (f32x4){0.f, 0.f, 0.f, 0.f};
        s1[qs] = (f32x4){0.f, 0.f, 0.f, 0.f};
      }
      for (int kc = 0; kc < 2; kc++) {
        int pc = (kc * 4 + quad) ^ (l15 & 7);
        s16x8 k0f = *(const s16x8*)&ksb[(c * 32 + l15) * 64 + pc * 8];
        s16x8 k1f = *(const s16x8*)&ksb[(c * 32 + 16 + l15) * 64 + pc * 8];
        for (int qs = 0; qs < 2; qs++) {
          s0[qs] = __builtin_amdgcn_mfma_f32_16x16x32_bf16(k0f, qf[qs][kc], s0[qs], 0, 0, 0);
          s1[qs] = __builtin_amdgcn_mfma_f32_16x16x32_bf16(k1f, qf[qs][kc], s1[qs], 0, 0, 0);
        }
      }
      for (int qs = 0; qs < 2; qs++) {
        i32x4 d;
        d[0] = (int)pk2t(e2(s0[qs][0]), e2(s0[qs][1]));
        d[1] = (int)pk2t(e2(s0[qs][2]), e2(s0[qs][3]));
        d[2] = (int)pk2t(e2(s1[qs][0]), e2(s1[qs][1]));
        d[3] = (int)pk2t(e2(s1[qs][2]), e2(s1[qs][3]));
        bfr[qs][c] = __builtin_bit_cast(s16x8, d);
      }
    }

    // O^T += V^T · P ; l += 1 · P
    for (int c = 0; c < 4; c++) {
      lacc[0] = __builtin_amdgcn_mfma_f32_16x16x32_bf16(ones, bfr[0][c], lacc[0], 0, 0, 0);
      lacc[1] = __builtin_amdgcn_mfma_f32_16x16x32_bf16(ones, bfr[1][c], lacc[1], 0, 0, 0);
      for (int et = 0; et < 4; et++) {
        int pc = (c * 4 + quad) ^ l15;
        s16x8 vf = *(const s16x8*)&vsb[(et * 16 + l15) * 128 + pc * 8];
        o[0][et] = __builtin_amdgcn_mfma_f32_16x16x32_bf16(vf, bfr[0][c], o[0][et], 0, 0, 0);
        o[1][et] = __builtin_amdgcn_mfma_f32_16x16x32_bf16(vf, bfr[1][c], o[1][et], 0, 0, 0);
      }
    }
  }
#undef STAGE

  // epilogue: every lane has its own query's l in lacc[qs][0]; weighted atomics
  int bb = bh >> 3, hh = bh & 7;
  for (int qs = 0; qs < 2; qs++) {
    float inv = 1.f / lacc[qs][0];
    int t = qt * 128 + wave * 32 + qs * 16 + l15;
    for (int et = 0; et < 4; et++)
      for (int r = 0; r < 4; r++) {
        int e = et * 16 + quad * 4 + r;
        float val = o[qs][et][r] * inv * wgt[hh * 64 + e];
        atomicAdd(&out[(((size_t)bb * T_ + t) << 6) + e], val);
      }
  }
}

extern "C" void kernel_launch(void* const* d_in, const int* in_sizes, int n_in,
                              void* d_out, int out_size, void* d_ws, size_t ws_size,
                              hipStream_t stream) {
  const float* obs = (const float*)d_in[0];
  const float* st  = (const float*)d_in[1];
  const float* Wq  = (const float*)d_in[2];
  const float* Wk  = (const float*)d_in[3];
  const float* Wv  = (const float*)d_in[4];
  const float* mw  = (const float*)d_in[5];

  // ws layout (26 MB, identical to rounds 2-5 proven layout)
  const size_t WS_NEEDED = 27262976;
  char* ws = (char*)d_ws;
  ushort_t* wt  = (ushort_t*)ws;                     // 1.5 MB
  float*    wgt = (float*)(ws + 1572864u);           // 2 KB
  ushort_t* qo  = (ushort_t*)(ws + 2097152u);        // [B,H,T,E] bf16, 8 MB
  ushort_t* ko  = (ushort_t*)(ws + 10485760u);       // [B,H,T,E] bf16, 8 MB
  ushort_t* vto = (ushort_t*)(ws + 18874368u);       // [B,H,E,T] bf16, 8 MB
  float*    out = (float*)d_out;

  hipMemsetAsync(d_out, 0, (size_t)out_size * sizeof(float), stream);
  if (ws_size < WS_NEEDED) return;

  hipLaunchKernelGGL(k_prep, dim3(8, 8, 3), dim3(256), 0, stream, Wq, Wk, Wv, wt);
  hipLaunchKernelGGL(k_wgt,  dim3(1),       dim3(64),  0, stream, mw, wgt);
  hipLaunchKernelGGL(k_proj, dim3(768),     dim3(256), 0, stream, obs, st, wt, qo, ko, vto);
  hipLaunchKernelGGL(k_attn, dim3(512),     dim3(256), 0, stream, qo, ko, vto, wgt, out);
}

// Round 7
// 193.971 us; speedup vs baseline: 1.7055x; 1.0711x over previous
//
#include <hip/hip_runtime.h>

#define B_ 4
#define T_ 2048
#define H_ 8
#define E_ 64
#define KDIM 512

typedef unsigned short ushort_t;
typedef __attribute__((ext_vector_type(4))) float f32x4;
typedef __attribute__((ext_vector_type(4))) int i32x4;
typedef __attribute__((ext_vector_type(8))) short s16x8;

// fold (1/64^0.25) * sqrt(log2(e)) into both Wq and Wk -> logits arrive pre-multiplied by log2(e)
#define QK_SCALE 0.42466043f

__device__ __forceinline__ ushort_t f2bf(float f) {   // RNE
  unsigned u = __builtin_bit_cast(unsigned, f);
  u += 0x7fffu + ((u >> 16) & 1u);
  return (ushort_t)(u >> 16);
}
__device__ __forceinline__ unsigned pk2(float a, float b) {  // RNE pack
  return (unsigned)f2bf(a) | ((unsigned)f2bf(b) << 16);
}
// truncating pack, single v_perm_b32: dst = {hi16(b), hi16(a)}
__device__ __forceinline__ unsigned pk2t(float a, float b) {
  return __builtin_amdgcn_perm(__builtin_bit_cast(unsigned, b),
                               __builtin_bit_cast(unsigned, a), 0x07060302u);
}
__device__ __forceinline__ float e2(float x) { return __builtin_amdgcn_exp2f(x); }
// async global->LDS, 16B per lane, LDS dest = wave-uniform base + lane*16
__device__ __forceinline__ void gl2lds16(const void* g, void* l) {
  __builtin_amdgcn_global_load_lds((const __attribute__((address_space(1))) unsigned*)g,
                                   (__attribute__((address_space(3))) unsigned*)l, 16, 0, 0);
}

// ---------------- weight prep: LDS-tiled transpose to [N][K] bf16, fold scales ------
__global__ void k_prep(const float* __restrict__ Wq, const float* __restrict__ Wk,
                       const float* __restrict__ Wv, ushort_t* __restrict__ wt) {
  __shared__ ushort_t tile[64][66];
  int z = blockIdx.z;
  const float* W = (z == 0) ? Wq : (z == 1 ? Wk : Wv);
  float scale = (z < 2) ? QK_SCALE : 1.0f;
  int k0 = blockIdx.y << 6, n0 = blockIdx.x << 6;
  int rr = threadIdx.x >> 6, cc = threadIdx.x & 63;
  for (int p = 0; p < 16; p++) {
    int kl = p * 4 + rr;
    tile[cc][kl] = f2bf(W[(size_t)(k0 + kl) * 512 + n0 + cc] * scale);
  }
  __syncthreads();
  int kp2 = threadIdx.x & 31, nr = threadIdx.x >> 5;
  unsigned* wt32 = (unsigned*)(wt + (size_t)z * 262144);
  for (int p = 0; p < 8; p++) {
    int nl = p * 8 + nr;
    unsigned val = (unsigned)tile[nl][kp2 * 2] | ((unsigned)tile[nl][kp2 * 2 + 1] << 16);
    wt32[(size_t)(n0 + nl) * 256 + (k0 >> 1) + kp2] = val;
  }
}

// ---------------- merge-weight softmax over heads: wgt[h][e] ------------------------
__global__ void k_wgt(const float* __restrict__ mw, float* __restrict__ wgt) {
  int e = threadIdx.x;  // 64 threads
  float w[8], wmax = -1e30f;
  for (int h = 0; h < 8; h++) { w[h] = mw[h * 64 + e]; wmax = fmaxf(wmax, w[h]); }
  float wsum = 0.f;
  for (int h = 0; h < 8; h++) { w[h] = __expf(w[h] - wmax); wsum += w[h]; }
  float inv = 1.f / wsum;
  for (int h = 0; h < 8; h++) wgt[h * 64 + e] = w[h] * inv;
}

// ---------------- QKV projection v7: BK=32, A dbuf 2x16KB, B register-direct --------
// 128m x 128n, acc[4][4]. LDS 32 KB -> 3 blocks/CU (launch_bounds(256,3), spill-safe).
// B-loads issued before the A-prefetch so their waitcnt keeps the prefetch in flight.
// XCD sibling swizzle: 4 n-tiles of an m-block share an XCD (A from L2 after 1st).
__global__ __launch_bounds__(256, 3) void k_proj(
    const float* __restrict__ obs, const float* __restrict__ st,
    const ushort_t* __restrict__ wt,
    ushort_t* __restrict__ qo, ushort_t* __restrict__ ko, ushort_t* __restrict__ vto) {
  __shared__ __align__(16) float As[2][128 * 32];   // 2 x 16 KB

  int id = blockIdx.x;              // 768
  int xcd = id & 7, nt = (id >> 3) & 3, ghi = id >> 5;
  int g = ghi * 8 + xcd;            // sibling group 0..191, all 4 nt share xcd
  int which = g >> 6, mb = g & 63;
  int m0 = mb << 7, n0 = nt << 7;
  const float* X = (which == 0) ? obs : st;
  const ushort_t* W = wt + which * 262144;

  int tid = threadIdx.x, wave = tid >> 6, lane = tid & 63;
  int l15 = lane & 15, quad = lane >> 4;
  int wm = wave & 1, wn = wave >> 1;

  f32x4 acc[4][4];
  for (int i = 0; i < 4; i++)
    for (int j = 0; j < 4; j++) acc[i][j] = (f32x4){0.f, 0.f, 0.f, 0.f};

  int arl = lane >> 3, ap = lane & 7;  // A stage: 8 rows/instr, 8 chunks(16B)/row

#define STAGEA(buf, k0)                                                           \
  do {                                                                            \
    for (int ii = 0; ii < 4; ii++) {                                              \
      int r = wave * 32 + ii * 8 + arl;                                           \
      gl2lds16(X + (size_t)(m0 + r) * KDIM + (k0) + ((ap ^ (r & 7)) << 2),        \
               &As[buf][(wave * 32 + ii * 8) * 32]);                              \
    }                                                                             \
  } while (0)

  // B row pointers (advance by 32 per k-iter)
  const ushort_t* wb[4];
  for (int j = 0; j < 4; j++)
    wb[j] = W + (size_t)(n0 + wn * 64 + j * 16 + l15) * KDIM + quad * 8;

  STAGEA(0, 0);
  __builtin_amdgcn_s_waitcnt(0x0F70);  // vmcnt(0)
  __syncthreads();

  for (int kt = 0; kt < 16; kt++) {
    // 1) B register loads FIRST
    s16x8 b[4];
    for (int j = 0; j < 4; j++) { b[j] = *(const s16x8*)wb[j]; wb[j] += 32; }
    // 2) prefetch next A tile
    if (kt < 15) STAGEA((kt + 1) & 1, kt * 32 + 32);
    // 3) compute current tile
    const float* asb = As[kt & 1];
    s16x8 a[4];
    for (int i = 0; i < 4; i++) {
      int mr = wm * 64 + i * 16 + l15;
      int s = mr & 7;
      const float* rowp = &asb[mr * 32];
      float4 x0 = *(const float4*)&rowp[(((quad << 1)) ^ s) << 2];       // k 8q..8q+3
      float4 x1 = *(const float4*)&rowp[(((quad << 1) | 1) ^ s) << 2];   // k 8q+4..+7
      i32x4 d;
      d[0] = (int)pk2(x0.x, x0.y);
      d[1] = (int)pk2(x0.z, x0.w);
      d[2] = (int)pk2(x1.x, x1.y);
      d[3] = (int)pk2(x1.z, x1.w);
      a[i] = __builtin_bit_cast(s16x8, d);
    }
    if (which == 2) {
      for (int i = 0; i < 4; i++)
        for (int j = 0; j < 4; j++)
          acc[i][j] = __builtin_amdgcn_mfma_f32_16x16x32_bf16(b[j], a[i], acc[i][j], 0, 0, 0);
    } else {
      for (int i = 0; i < 4; i++)
        for (int j = 0; j < 4; j++)
          acc[i][j] = __builtin_amdgcn_mfma_f32_16x16x32_bf16(a[i], b[j], acc[i][j], 0, 0, 0);
    }
    __builtin_amdgcn_s_waitcnt(0x0F70);  // vmcnt(0): next A landed
    __syncthreads();
  }
#undef STAGEA

  if (which != 2) {
    ushort_t* dst = (which == 0) ? qo : ko;
    for (int i = 0; i < 4; i++) {
      int grow = m0 + wm * 64 + i * 16 + quad * 4;
      for (int j = 0; j < 4; j++) {
        int gcol = n0 + wn * 64 + j * 16 + l15;
        int h = gcol >> 6, e = gcol & 63;
        for (int r = 0; r < 4; r++) {
          int row = grow + r;
          int bb = row >> 11, t = row & 2047;
          int bh = bb * H_ + h;
          dst[(((size_t)bh * T_ + t) << 6) + e] = f2bf(acc[i][j][r]);
        }
      }
    }
  } else {
    // swapped: C row = W-col (h,e), C col = X-row (t); 16 consecutive t per store
    for (int i = 0; i < 4; i++) {
      int row = m0 + wm * 64 + i * 16 + l15;
      int bb = row >> 11, t = row & 2047;
      for (int j = 0; j < 4; j++) {
        for (int r = 0; r < 4; r++) {
          int gcol = n0 + wn * 64 + j * 16 + quad * 4 + r;
          int h = gcol >> 6, e = gcol & 63;
          int bh = bb * H_ + h;
          vto[((size_t)(bh << 6) + e) * T_ + t] = f2bf(acc[i][j][r]);
        }
      }
    }
  }
}

// ---------------- flash attention v6: 64-key tiles, 32 KB LDS, coalesced epilogue ----
union AttnSmem {
  struct { ushort_t ks[2][64 * 64]; ushort_t vs[2][64 * 64]; } st;  // 32 KB
  struct { float ows[64 * 65]; float linv[64]; } ep;                // 16.9 KB
};

__global__ __launch_bounds__(256, 4) void k_attn(
    const ushort_t* __restrict__ q, const ushort_t* __restrict__ k,
    const ushort_t* __restrict__ vt, const float* __restrict__ wgt,
    float* __restrict__ out) {
  __shared__ __align__(16) AttnSmem sm;

  int id = blockIdx.x;      // 512; bh fastest -> 4 heads/XCD (K+V L2-resident)
  int bh = id & 31, qt = id >> 5;
  int tid = threadIdx.x, wave = tid >> 6, lane = tid & 63;
  int l15 = lane & 15, quad = lane >> 4;

  // Q B-frags for 2 query sub-tiles: B[k=e=quad*8+j][n=q=l15]
  s16x8 qf[2][2];
  for (int qs = 0; qs < 2; qs++) {
    const ushort_t* qp =
        q + (((size_t)bh * T_ + qt * 128 + wave * 32 + qs * 16 + l15) << 6) + quad * 8;
    qf[qs][0] = *(const s16x8*)qp;
    qf[qs][1] = *(const s16x8*)(qp + 32);
  }
  int hh = bh & 7;
  float wgl = wgt[hh * 64 + lane];

  f32x4 o[2][4];
  for (int qs = 0; qs < 2; qs++)
    for (int j = 0; j < 4; j++) o[qs][j] = (f32x4){0.f, 0.f, 0.f, 0.f};
  f32x4 lacc[2] = {(f32x4){0.f, 0.f, 0.f, 0.f}, (f32x4){0.f, 0.f, 0.f, 0.f}};
  const s16x8 ones = {16256, 16256, 16256, 16256, 16256, 16256, 16256, 16256};  // bf16 1.0

  int srl = lane >> 3, sp = lane & 7;
  const ushort_t* kbase = k + ((size_t)bh * T_ << 6);
  const ushort_t* vbase = vt + ((size_t)bh << 6) * T_;
  const ushort_t* kptr[2];
  const ushort_t* vptr[2];
  for (int ii = 0; ii < 2; ii++) {
    int r = wave * 16 + ii * 8 + srl;   // K LDS row 0..63
    int gkey = (r & 32) + (((r >> 2) & 3) << 3) + (((r >> 4) & 1) << 2) + (r & 3);
    kptr[ii] = kbase + ((size_t)gkey << 6) + ((sp ^ (r & 7)) << 3);
    int e = r;                           // V e-row 0..63
    vptr[ii] = vbase + (size_t)e * T_ + ((sp ^ (e & 7)) << 3);
  }

#define STAGE(buf)                                                         \
  do {                                                                     \
    for (int ii = 0; ii < 2; ii++) {                                       \
      gl2lds16(kptr[ii], &sm.st.ks[buf][(wave * 16 + ii * 8) * 64]);       \
      gl2lds16(vptr[ii], &sm.st.vs[buf][(wave * 16 + ii * 8) * 64]);       \
      kptr[ii] += 64 * 64;  /* next 64-key tile */                         \
      vptr[ii] += 64;       /* V^T: advance 64 keys along row */           \
    }                                                                      \
  } while (0)

  STAGE(0);
  for (int kt = 0; kt < 32; kt++) {
    __builtin_amdgcn_s_waitcnt(0x0F70);  // vmcnt(0): prev staging landed
    __syncthreads();
    if (kt < 31) STAGE((kt + 1) & 1);
    const ushort_t* ksb = sm.st.ks[kt & 1];
    const ushort_t* vsb = sm.st.vs[kt & 1];

    // S^T chunks -> v_exp_f32 -> perm-pack P^T B-frags, entirely in-lane
    s16x8 bfr[2][2];
    for (int c = 0; c < 2; c++) {
      f32x4 s0[2], s1[2];
      for (int qs = 0; qs < 2; qs++) {
        s0[qs] = (f32x4){0.f, 0.f, 0.f, 0.f};
        s1[qs] = (f32x4){0.f, 0.f, 0.f, 0.f};
      }
      for (int kc = 0; kc < 2; kc++) {
        int pc = (kc * 4 + quad) ^ (l15 & 7);
        s16x8 k0f = *(const s16x8*)&ksb[(c * 32 + l15) * 64 + pc * 8];
        s16x8 k1f = *(const s16x8*)&ksb[(c * 32 + 16 + l15) * 64 + pc * 8];
        for (int qs = 0; qs < 2; qs++) {
          s0[qs] = __builtin_amdgcn_mfma_f32_16x16x32_bf16(k0f, qf[qs][kc], s0[qs], 0, 0, 0);
          s1[qs] = __builtin_amdgcn_mfma_f32_16x16x32_bf16(k1f, qf[qs][kc], s1[qs], 0, 0, 0);
        }
      }
      for (int qs = 0; qs < 2; qs++) {
        i32x4 d;
        d[0] = (int)pk2t(e2(s0[qs][0]), e2(s0[qs][1]));
        d[1] = (int)pk2t(e2(s0[qs][2]), e2(s0[qs][3]));
        d[2] = (int)pk2t(e2(s1[qs][0]), e2(s1[qs][1]));
        d[3] = (int)pk2t(e2(s1[qs][2]), e2(s1[qs][3]));
        bfr[qs][c] = __builtin_bit_cast(s16x8, d);
      }
    }

    // O^T += V^T · P ; l += 1 · P
    for (int c = 0; c < 2; c++) {
      lacc[0] = __builtin_amdgcn_mfma_f32_16x16x32_bf16(ones, bfr[0][c], lacc[0], 0, 0, 0);
      lacc[1] = __builtin_amdgcn_mfma_f32_16x16x32_bf16(ones, bfr[1][c], lacc[1], 0, 0, 0);
      for (int et = 0; et < 4; et++) {
        int pc = (c * 4 + quad) ^ (l15 & 7);
        s16x8 vf = *(const s16x8*)&vsb[(et * 16 + l15) * 64 + pc * 8];
        o[0][et] = __builtin_amdgcn_mfma_f32_16x16x32_bf16(vf, bfr[0][c], o[0][et], 0, 0, 0);
        o[1][et] = __builtin_amdgcn_mfma_f32_16x16x32_bf16(vf, bfr[1][c], o[1][et], 0, 0, 0);
      }
    }
  }
#undef STAGE

  // ---- epilogue: O^T -> LDS transpose (union, after barrier) -> coalesced atomics --
  int bb = bh >> 3;
  for (int half = 0; half < 2; half++) {
    __syncthreads();
    if ((wave >> 1) == half) {
      int tl = (wave & 1) * 32;
      for (int qs = 0; qs < 2; qs++) {
        int row = tl + qs * 16 + l15;
        if (quad == 0) sm.ep.linv[row] = 1.f / lacc[qs][0];
        for (int et = 0; et < 4; et++)
          for (int r = 0; r < 4; r++)
            sm.ep.ows[row * 65 + et * 16 + quad * 4 + r] = o[qs][et][r];
      }
    }
    __syncthreads();
    for (int i = 0; i < 16; i++) {
      int row = wave * 16 + i;
      int gt = qt * 128 + half * 64 + row;
      float val = sm.ep.ows[row * 65 + lane] * sm.ep.linv[row] * wgl;
      atomicAdd(&out[(((size_t)bb * T_ + gt) << 6) + lane], val);
    }
  }
}

extern "C" void kernel_launch(void* const* d_in, const int* in_sizes, int n_in,
                              void* d_out, int out_size, void* d_ws, size_t ws_size,
                              hipStream_t stream) {
  const float* obs = (const float*)d_in[0];
  const float* st  = (const float*)d_in[1];
  const float* Wq  = (const float*)d_in[2];
  const float* Wk  = (const float*)d_in[3];
  const float* Wv  = (const float*)d_in[4];
  const float* mw  = (const float*)d_in[5];

  // ws layout (26 MB, identical to rounds 2-6 proven layout)
  const size_t WS_NEEDED = 27262976;
  char* ws = (char*)d_ws;
  ushort_t* wt  = (ushort_t*)ws;                     // 1.5 MB
  float*    wgt = (float*)(ws + 1572864u);           // 2 KB
  ushort_t* qo  = (ushort_t*)(ws + 2097152u);        // [B,H,T,E] bf16, 8 MB
  ushort_t* ko  = (ushort_t*)(ws + 10485760u);       // [B,H,T,E] bf16, 8 MB
  ushort_t* vto = (ushort_t*)(ws + 18874368u);       // [B,H,E,T] bf16, 8 MB
  float*    out = (float*)d_out;

  hipMemsetAsync(d_out, 0, (size_t)out_size * sizeof(float), stream);
  if (ws_size < WS_NEEDED) return;

  hipLaunchKernelGGL(k_prep, dim3(8, 8, 3), dim3(256), 0, stream, Wq, Wk, Wv, wt);
  hipLaunchKernelGGL(k_wgt,  dim3(1),       dim3(64),  0, stream, mw, wgt);
  hipLaunchKernelGGL(k_proj, dim3(768),     dim3(256), 0, stream, obs, st, wt, qo, ko, vto);
  hipLaunchKernelGGL(k_attn, dim3(512),     dim3(256), 0, stream, qo, ko, vto, wgt, out);
}

// Round 8
// 191.241 us; speedup vs baseline: 1.7299x; 1.0143x over previous
//
#include <hip/hip_runtime.h>

#define B_ 4
#define T_ 2048
#define H_ 8
#define E_ 64
#define KDIM 512

typedef unsigned short ushort_t;
typedef __attribute__((ext_vector_type(4))) float f32x4;
typedef __attribute__((ext_vector_type(4))) int i32x4;
typedef __attribute__((ext_vector_type(8))) short s16x8;

// fold (1/64^0.25) * sqrt(log2(e)) into both Wq and Wk -> logits arrive pre-multiplied by log2(e)
#define QK_SCALE 0.42466043f

__device__ __forceinline__ ushort_t f2bf(float f) {   // RNE
  unsigned u = __builtin_bit_cast(unsigned, f);
  u += 0x7fffu + ((u >> 16) & 1u);
  return (ushort_t)(u >> 16);
}
__device__ __forceinline__ unsigned pk2(float a, float b) {  // RNE pack
  return (unsigned)f2bf(a) | ((unsigned)f2bf(b) << 16);
}
// truncating pack, single v_perm_b32: dst = {hi16(b), hi16(a)}
__device__ __forceinline__ unsigned pk2t(float a, float b) {
  return __builtin_amdgcn_perm(__builtin_bit_cast(unsigned, b),
                               __builtin_bit_cast(unsigned, a), 0x07060302u);
}
__device__ __forceinline__ float e2(float x) { return __builtin_amdgcn_exp2f(x); }
// async global->LDS, 16B per lane, LDS dest = wave-uniform base + lane*16
__device__ __forceinline__ void gl2lds16(const void* g, void* l) {
  __builtin_amdgcn_global_load_lds((const __attribute__((address_space(1))) unsigned*)g,
                                   (__attribute__((address_space(3))) unsigned*)l, 16, 0, 0);
}

// ---------------- weight prep: LDS-tiled transpose to [N][K] bf16, fold scales ------
__global__ void k_prep(const float* __restrict__ Wq, const float* __restrict__ Wk,
                       const float* __restrict__ Wv, ushort_t* __restrict__ wt) {
  __shared__ ushort_t tile[64][66];
  int z = blockIdx.z;
  const float* W = (z == 0) ? Wq : (z == 1 ? Wk : Wv);
  float scale = (z < 2) ? QK_SCALE : 1.0f;
  int k0 = blockIdx.y << 6, n0 = blockIdx.x << 6;
  int rr = threadIdx.x >> 6, cc = threadIdx.x & 63;
  for (int p = 0; p < 16; p++) {
    int kl = p * 4 + rr;
    tile[cc][kl] = f2bf(W[(size_t)(k0 + kl) * 512 + n0 + cc] * scale);
  }
  __syncthreads();
  int kp2 = threadIdx.x & 31, nr = threadIdx.x >> 5;
  unsigned* wt32 = (unsigned*)(wt + (size_t)z * 262144);
  for (int p = 0; p < 8; p++) {
    int nl = p * 8 + nr;
    unsigned val = (unsigned)tile[nl][kp2 * 2] | ((unsigned)tile[nl][kp2 * 2 + 1] << 16);
    wt32[(size_t)(n0 + nl) * 256 + (k0 >> 1) + kp2] = val;
  }
}

// ---------------- merge-weight softmax over heads: wgt[h][e] ------------------------
__global__ void k_wgt(const float* __restrict__ mw, float* __restrict__ wgt) {
  int e = threadIdx.x;  // 64 threads
  float w[8], wmax = -1e30f;
  for (int h = 0; h < 8; h++) { w[h] = mw[h * 64 + e]; wmax = fmaxf(wmax, w[h]); }
  float wsum = 0.f;
  for (int h = 0; h < 8; h++) { w[h] = __expf(w[h] - wmax); wsum += w[h]; }
  float inv = 1.f / wsum;
  for (int h = 0; h < 8; h++) wgt[h * 64 + e] = w[h] * inv;
}

// ---------------- activation fp32 -> bf16 pre-convert (streaming, RNE) --------------
__global__ void k_cvt(const float* __restrict__ obs, const float* __restrict__ st,
                      unsigned* __restrict__ xo, unsigned* __restrict__ xs) {
  int which = blockIdx.y;
  const float* src = which ? st : obs;
  unsigned* dst = which ? xs : xo;
  size_t idx = (size_t)blockIdx.x * 256 + threadIdx.x;  // 524288 threads, 8 elems each
  size_t base = idx * 8;
  float4 x0 = *(const float4*)(src + base);
  float4 x1 = *(const float4*)(src + base + 4);
  uint4 d;
  d.x = pk2(x0.x, x0.y);
  d.y = pk2(x0.z, x0.w);
  d.z = pk2(x1.x, x1.y);
  d.w = pk2(x1.z, x1.w);
  *(uint4*)(dst + idx * 4) = d;
}

// ---------------- QKV projection v8: all-bf16, BK=64, A dbuf via gl_lds -------------
// 128m x 128n, 8 K-iters, 32 MFMA/iter/wave, ZERO pack VALU in the K-loop. A staged
// with the conflict-free xor pattern (measured 0 conflicts in k_attn rounds 4-7).
// B register-direct from L2-hot weights, issued before the A-prefetch. V swapped.
__global__ __launch_bounds__(256, 3) void k_proj2(
    const ushort_t* __restrict__ xo, const ushort_t* __restrict__ xs,
    const ushort_t* __restrict__ wt,
    ushort_t* __restrict__ qo, ushort_t* __restrict__ ko, ushort_t* __restrict__ vto) {
  __shared__ __align__(16) ushort_t As[2][128 * 64];   // 2 x 16 KB

  int id = blockIdx.x;              // 768
  int xcd = id & 7, nt = (id >> 3) & 3, ghi = id >> 5;
  int g = ghi * 8 + xcd;            // sibling group; 4 n-tiles share an XCD
  int which = g >> 6, mb = g & 63;
  int m0 = mb << 7, n0 = nt << 7;
  const ushort_t* X = (which == 0) ? xo : xs;
  const ushort_t* W = wt + which * 262144;

  int tid = threadIdx.x, wave = tid >> 6, lane = tid & 63;
  int l15 = lane & 15, quad = lane >> 4;
  int wm = wave & 1, wn = wave >> 1;

  f32x4 acc[4][4];
  for (int i = 0; i < 4; i++)
    for (int j = 0; j < 4; j++) acc[i][j] = (f32x4){0.f, 0.f, 0.f, 0.f};

  int arl = lane >> 3, ap = lane & 7;  // A stage: 8 rows/instr, 8 chunks(16B)/row

#define STAGEA(buf, k0)                                                            \
  do {                                                                             \
    for (int ii = 0; ii < 4; ii++) {                                               \
      int r = wave * 32 + ii * 8 + arl;                                            \
      gl2lds16(X + (size_t)(m0 + r) * KDIM + (k0) + ((ap ^ (r & 7)) << 3),         \
               &As[buf][(wave * 32 + ii * 8) * 64]);                               \
    }                                                                              \
  } while (0)

  // B row pointers (advance by 64 per k-iter)
  const ushort_t* wb[4];
  for (int j = 0; j < 4; j++)
    wb[j] = W + (size_t)(n0 + wn * 64 + j * 16 + l15) * KDIM + quad * 8;

  STAGEA(0, 0);
  __builtin_amdgcn_s_waitcnt(0x0F70);  // vmcnt(0)
  __syncthreads();

  for (int kt = 0; kt < 8; kt++) {
    // 1) B register loads FIRST (their waitcnt keeps the A-prefetch in flight)
    s16x8 b[2][4];
    for (int kc = 0; kc < 2; kc++)
      for (int j = 0; j < 4; j++) b[kc][j] = *(const s16x8*)(wb[j] + kc * 32);
    for (int j = 0; j < 4; j++) wb[j] += 64;
    // 2) prefetch next A tile
    if (kt < 7) STAGEA((kt + 1) & 1, kt * 64 + 64);
    // 3) compute current tile (pure b128 LDS reads, no conversion)
    const ushort_t* asb = As[kt & 1];
    for (int kc = 0; kc < 2; kc++) {
      s16x8 a[4];
      for (int i = 0; i < 4; i++) {
        int mr = wm * 64 + i * 16 + l15;
        int pc = (kc * 4 + quad) ^ (l15 & 7);
        a[i] = *(const s16x8*)&asb[mr * 64 + pc * 8];
      }
      if (which == 2) {
        for (int i = 0; i < 4; i++)
          for (int j = 0; j < 4; j++)
            acc[i][j] = __builtin_amdgcn_mfma_f32_16x16x32_bf16(b[kc][j], a[i], acc[i][j], 0, 0, 0);
      } else {
        for (int i = 0; i < 4; i++)
          for (int j = 0; j < 4; j++)
            acc[i][j] = __builtin_amdgcn_mfma_f32_16x16x32_bf16(a[i], b[kc][j], acc[i][j], 0, 0, 0);
      }
    }
    __builtin_amdgcn_s_waitcnt(0x0F70);  // vmcnt(0): next A landed
    __syncthreads();
  }
#undef STAGEA

  if (which != 2) {
    ushort_t* dst = (which == 0) ? qo : ko;
    for (int i = 0; i < 4; i++) {
      int grow = m0 + wm * 64 + i * 16 + quad * 4;
      for (int j = 0; j < 4; j++) {
        int gcol = n0 + wn * 64 + j * 16 + l15;
        int h = gcol >> 6, e = gcol & 63;
        for (int r = 0; r < 4; r++) {
          int row = grow + r;
          int bb = row >> 11, t = row & 2047;
          int bh = bb * H_ + h;
          dst[(((size_t)bh * T_ + t) << 6) + e] = f2bf(acc[i][j][r]);
        }
      }
    }
  } else {
    for (int i = 0; i < 4; i++) {
      int row = m0 + wm * 64 + i * 16 + l15;
      int bb = row >> 11, t = row & 2047;
      for (int j = 0; j < 4; j++) {
        for (int r = 0; r < 4; r++) {
          int gcol = n0 + wn * 64 + j * 16 + quad * 4 + r;
          int h = gcol >> 6, e = gcol & 63;
          int bh = bb * H_ + h;
          vto[((size_t)(bh << 6) + e) * T_ + t] = f2bf(acc[i][j][r]);
        }
      }
    }
  }
}

// ---------------- QKV projection v7 (fp32 fallback, proven) -------------------------
__global__ __launch_bounds__(256, 3) void k_proj(
    const float* __restrict__ obs, const float* __restrict__ st,
    const ushort_t* __restrict__ wt,
    ushort_t* __restrict__ qo, ushort_t* __restrict__ ko, ushort_t* __restrict__ vto) {
  __shared__ __align__(16) float As[2][128 * 32];   // 2 x 16 KB

  int id = blockIdx.x;              // 768
  int xcd = id & 7, nt = (id >> 3) & 3, ghi = id >> 5;
  int g = ghi * 8 + xcd;
  int which = g >> 6, mb = g & 63;
  int m0 = mb << 7, n0 = nt << 7;
  const float* X = (which == 0) ? obs : st;
  const ushort_t* W = wt + which * 262144;

  int tid = threadIdx.x, wave = tid >> 6, lane = tid & 63;
  int l15 = lane & 15, quad = lane >> 4;
  int wm = wave & 1, wn = wave >> 1;

  f32x4 acc[4][4];
  for (int i = 0; i < 4; i++)
    for (int j = 0; j < 4; j++) acc[i][j] = (f32x4){0.f, 0.f, 0.f, 0.f};

  int arl = lane >> 3, ap = lane & 7;

#define STAGEA(buf, k0)                                                           \
  do {                                                                            \
    for (int ii = 0; ii < 4; ii++) {                                              \
      int r = wave * 32 + ii * 8 + arl;                                           \
      gl2lds16(X + (size_t)(m0 + r) * KDIM + (k0) + ((ap ^ (r & 7)) << 2),        \
               &As[buf][(wave * 32 + ii * 8) * 32]);                              \
    }                                                                             \
  } while (0)

  const ushort_t* wb[4];
  for (int j = 0; j < 4; j++)
    wb[j] = W + (size_t)(n0 + wn * 64 + j * 16 + l15) * KDIM + quad * 8;

  STAGEA(0, 0);
  __builtin_amdgcn_s_waitcnt(0x0F70);
  __syncthreads();

  for (int kt = 0; kt < 16; kt++) {
    s16x8 b[4];
    for (int j = 0; j < 4; j++) { b[j] = *(const s16x8*)wb[j]; wb[j] += 32; }
    if (kt < 15) STAGEA((kt + 1) & 1, kt * 32 + 32);
    const float* asb = As[kt & 1];
    s16x8 a[4];
    for (int i = 0; i < 4; i++) {
      int mr = wm * 64 + i * 16 + l15;
      int s = mr & 7;
      const float* rowp = &asb[mr * 32];
      float4 x0 = *(const float4*)&rowp[(((quad << 1)) ^ s) << 2];
      float4 x1 = *(const float4*)&rowp[(((quad << 1) | 1) ^ s) << 2];
      i32x4 d;
      d[0] = (int)pk2(x0.x, x0.y);
      d[1] = (int)pk2(x0.z, x0.w);
      d[2] = (int)pk2(x1.x, x1.y);
      d[3] = (int)pk2(x1.z, x1.w);
      a[i] = __builtin_bit_cast(s16x8, d);
    }
    if (which == 2) {
      for (int i = 0; i < 4; i++)
        for (int j = 0; j < 4; j++)
          acc[i][j] = __builtin_amdgcn_mfma_f32_16x16x32_bf16(b[j], a[i], acc[i][j], 0, 0, 0);
    } else {
      for (int i = 0; i < 4; i++)
        for (int j = 0; j < 4; j++)
          acc[i][j] = __builtin_amdgcn_mfma_f32_16x16x32_bf16(a[i], b[j], acc[i][j], 0, 0, 0);
    }
    __builtin_amdgcn_s_waitcnt(0x0F70);
    __syncthreads();
  }
#undef STAGEA

  if (which != 2) {
    ushort_t* dst = (which == 0) ? qo : ko;
    for (int i = 0; i < 4; i++) {
      int grow = m0 + wm * 64 + i * 16 + quad * 4;
      for (int j = 0; j < 4; j++) {
        int gcol = n0 + wn * 64 + j * 16 + l15;
        int h = gcol >> 6, e = gcol & 63;
        for (int r = 0; r < 4; r++) {
          int row = grow + r;
          int bb = row >> 11, t = row & 2047;
          int bh = bb * H_ + h;
          dst[(((size_t)bh * T_ + t) << 6) + e] = f2bf(acc[i][j][r]);
        }
      }
    }
  } else {
    for (int i = 0; i < 4; i++) {
      int row = m0 + wm * 64 + i * 16 + l15;
      int bb = row >> 11, t = row & 2047;
      for (int j = 0; j < 4; j++) {
        for (int r = 0; r < 4; r++) {
          int gcol = n0 + wn * 64 + j * 16 + quad * 4 + r;
          int h = gcol >> 6, e = gcol & 63;
          int bh = bb * H_ + h;
          vto[((size_t)(bh << 6) + e) * T_ + t] = f2bf(acc[i][j][r]);
        }
      }
    }
  }
}

// ---------------- flash attention v6: 64-key tiles, 32 KB LDS, coalesced epilogue ----
union AttnSmem {
  struct { ushort_t ks[2][64 * 64]; ushort_t vs[2][64 * 64]; } st;  // 32 KB
  struct { float ows[64 * 65]; float linv[64]; } ep;                // 16.9 KB
};

__global__ __launch_bounds__(256, 4) void k_attn(
    const ushort_t* __restrict__ q, const ushort_t* __restrict__ k,
    const ushort_t* __restrict__ vt, const float* __restrict__ wgt,
    float* __restrict__ out) {
  __shared__ __align__(16) AttnSmem sm;

  int id = blockIdx.x;      // 512; bh fastest -> 4 heads/XCD (K+V L2-resident)
  int bh = id & 31, qt = id >> 5;
  int tid = threadIdx.x, wave = tid >> 6, lane = tid & 63;
  int l15 = lane & 15, quad = lane >> 4;

  s16x8 qf[2][2];
  for (int qs = 0; qs < 2; qs++) {
    const ushort_t* qp =
        q + (((size_t)bh * T_ + qt * 128 + wave * 32 + qs * 16 + l15) << 6) + quad * 8;
    qf[qs][0] = *(const s16x8*)qp;
    qf[qs][1] = *(const s16x8*)(qp + 32);
  }
  int hh = bh & 7;
  float wgl = wgt[hh * 64 + lane];

  f32x4 o[2][4];
  for (int qs = 0; qs < 2; qs++)
    for (int j = 0; j < 4; j++) o[qs][j] = (f32x4){0.f, 0.f, 0.f, 0.f};
  f32x4 lacc[2] = {(f32x4){0.f, 0.f, 0.f, 0.f}, (f32x4){0.f, 0.f, 0.f, 0.f}};
  const s16x8 ones = {16256, 16256, 16256, 16256, 16256, 16256, 16256, 16256};  // bf16 1.0

  int srl = lane >> 3, sp = lane & 7;
  const ushort_t* kbase = k + ((size_t)bh * T_ << 6);
  const ushort_t* vbase = vt + ((size_t)bh << 6) * T_;
  const ushort_t* kptr[2];
  const ushort_t* vptr[2];
  for (int ii = 0; ii < 2; ii++) {
    int r = wave * 16 + ii * 8 + srl;
    int gkey = (r & 32) + (((r >> 2) & 3) << 3) + (((r >> 4) & 1) << 2) + (r & 3);
    kptr[ii] = kbase + ((size_t)gkey << 6) + ((sp ^ (r & 7)) << 3);
    int e = r;
    vptr[ii] = vbase + (size_t)e * T_ + ((sp ^ (e & 7)) << 3);
  }

#define STAGE(buf)                                                         \
  do {                                                                     \
    for (int ii = 0; ii < 2; ii++) {                                       \
      gl2lds16(kptr[ii], &sm.st.ks[buf][(wave * 16 + ii * 8) * 64]);       \
      gl2lds16(vptr[ii], &sm.st.vs[buf][(wave * 16 + ii * 8) * 64]);       \
      kptr[ii] += 64 * 64;                                                 \
      vptr[ii] += 64;                                                      \
    }                                                                      \
  } while (0)

  STAGE(0);
  for (int kt = 0; kt < 32; kt++) {
    __builtin_amdgcn_s_waitcnt(0x0F70);  // vmcnt(0): prev staging landed
    __syncthreads();
    if (kt < 31) STAGE((kt + 1) & 1);
    const ushort_t* ksb = sm.st.ks[kt & 1];
    const ushort_t* vsb = sm.st.vs[kt & 1];

    s16x8 bfr[2][2];
    for (int c = 0; c < 2; c++) {
      f32x4 s0[2], s1[2];
      for (int qs = 0; qs < 2; qs++) {
        s0[qs] = (f32x4){0.f, 0.f, 0.f, 0.f};
        s1[qs] = (f32x4){0.f, 0.f, 0.f, 0.f};
      }
      for (int kc = 0; kc < 2; kc++) {
        int pc = (kc * 4 + quad) ^ (l15 & 7);
        s16x8 k0f = *(const s16x8*)&ksb[(c * 32 + l15) * 64 + pc * 8];
        s16x8 k1f = *(const s16x8*)&ksb[(c * 32 + 16 + l15) * 64 + pc * 8];
        for (int qs = 0; qs < 2; qs++) {
          s0[qs] = __builtin_amdgcn_mfma_f32_16x16x32_bf16(k0f, qf[qs][kc], s0[qs], 0, 0, 0);
          s1[qs] = __builtin_amdgcn_mfma_f32_16x16x32_bf16(k1f, qf[qs][kc], s1[qs], 0, 0, 0);
        }
      }
      for (int qs = 0; qs < 2; qs++) {
        i32x4 d;
        d[0] = (int)pk2t(e2(s0[qs][0]), e2(s0[qs][1]));
        d[1] = (int)pk2t(e2(s0[qs][2]), e2(s0[qs][3]));
        d[2] = (int)pk2t(e2(s1[qs][0]), e2(s1[qs][1]));
        d[3] = (int)pk2t(e2(s1[qs][2]), e2(s1[qs][3]));
        bfr[qs][c] = __builtin_bit_cast(s16x8, d);
      }
    }

    for (int c = 0; c < 2; c++) {
      lacc[0] = __builtin_amdgcn_mfma_f32_16x16x32_bf16(ones, bfr[0][c], lacc[0], 0, 0, 0);
      lacc[1] = __builtin_amdgcn_mfma_f32_16x16x32_bf16(ones, bfr[1][c], lacc[1], 0, 0, 0);
      for (int et = 0; et < 4; et++) {
        int pc = (c * 4 + quad) ^ (l15 & 7);
        s16x8 vf = *(const s16x8*)&vsb[(et * 16 + l15) * 64 + pc * 8];
        o[0][et] = __builtin_amdgcn_mfma_f32_16x16x32_bf16(vf, bfr[0][c], o[0][et], 0, 0, 0);
        o[1][et] = __builtin_amdgcn_mfma_f32_16x16x32_bf16(vf, bfr[1][c], o[1][et], 0, 0, 0);
      }
    }
  }
#undef STAGE

  int bb = bh >> 3;
  for (int half = 0; half < 2; half++) {
    __syncthreads();
    if ((wave >> 1) == half) {
      int tl = (wave & 1) * 32;
      for (int qs = 0; qs < 2; qs++) {
        int row = tl + qs * 16 + l15;
        if (quad == 0) sm.ep.linv[row] = 1.f / lacc[qs][0];
        for (int et = 0; et < 4; et++)
          for (int r = 0; r < 4; r++)
            sm.ep.ows[row * 65 + et * 16 + quad * 4 + r] = o[qs][et][r];
      }
    }
    __syncthreads();
    for (int i = 0; i < 16; i++) {
      int row = wave * 16 + i;
      int gt = qt * 128 + half * 64 + row;
      float val = sm.ep.ows[row * 65 + lane] * sm.ep.linv[row] * wgl;
      atomicAdd(&out[(((size_t)bb * T_ + gt) << 6) + lane], val);
    }
  }
}

extern "C" void kernel_launch(void* const* d_in, const int* in_sizes, int n_in,
                              void* d_out, int out_size, void* d_ws, size_t ws_size,
                              hipStream_t stream) {
  const float* obs = (const float*)d_in[0];
  const float* st  = (const float*)d_in[1];
  const float* Wq  = (const float*)d_in[2];
  const float* Wk  = (const float*)d_in[3];
  const float* Wv  = (const float*)d_in[4];
  const float* mw  = (const float*)d_in[5];

  const size_t WS_NEEDED = 27262976;   // proven 26 MB layout
  const size_t WS_BIG    = 44040192;   // +16 MB bf16 activations
  char* ws = (char*)d_ws;
  ushort_t* wt  = (ushort_t*)ws;                     // 1.5 MB
  float*    wgt = (float*)(ws + 1572864u);           // 2 KB
  ushort_t* qo  = (ushort_t*)(ws + 2097152u);        // [B,H,T,E] bf16, 8 MB
  ushort_t* ko  = (ushort_t*)(ws + 10485760u);       // [B,H,T,E] bf16, 8 MB
  ushort_t* vto = (ushort_t*)(ws + 18874368u);       // [B,H,E,T] bf16, 8 MB
  ushort_t* xo  = (ushort_t*)(ws + 27262976u);       // obs bf16, 8 MB
  ushort_t* xs  = (ushort_t*)(ws + 35651584u);       // st  bf16, 8 MB
  float*    out = (float*)d_out;

  hipMemsetAsync(d_out, 0, (size_t)out_size * sizeof(float), stream);
  if (ws_size < WS_NEEDED) return;

  hipLaunchKernelGGL(k_prep, dim3(8, 8, 3), dim3(256), 0, stream, Wq, Wk, Wv, wt);
  hipLaunchKernelGGL(k_wgt,  dim3(1),       dim3(64),  0, stream, mw, wgt);
  if (ws_size >= WS_BIG) {
    hipLaunchKernelGGL(k_cvt,   dim3(2048, 2), dim3(256), 0, stream, obs, st,
                       (unsigned*)xo, (unsigned*)xs);
    hipLaunchKernelGGL(k_proj2, dim3(768),     dim3(256), 0, stream, xo, xs, wt, qo, ko, vto);
  } else {
    hipLaunchKernelGGL(k_proj,  dim3(768),     dim3(256), 0, stream, obs, st, wt, qo, ko, vto);
  }
  hipLaunchKernelGGL(k_attn, dim3(512), dim3(256), 0, stream, qo, ko, vto, wgt, out);
}